// Round 1
// baseline (75.402 us; speedup 1.0000x reference)
//
#include <hip/hip_runtime.h>
#include <hip/hip_bf16.h>
#include <stdint.h>

#define BN 8192
#define DK 256
#define NCHUNK 4
#define JTILES 16                       // j-tiles of 128 per block (2048/128)
#define KLOG2E_T 20.609929155556617f    // log2(e)/0.07
#define INV_T 14.285714285714286f       // 1/0.07
#define NEGINF (-3.0e38f)

typedef short vshort8 __attribute__((ext_vector_type(8)));
typedef float vfloat4 __attribute__((ext_vector_type(4)));

__device__ __forceinline__ void gload16(const void* g, void* lds) {
  __builtin_amdgcn_global_load_lds(
      (const __attribute__((address_space(1))) unsigned int*)g,
      (__attribute__((address_space(3))) unsigned int*)lds, 16, 0, 0);
}

// ---------------- prep: fp32 -> bf16, pack keys ----------------
__global__ __launch_bounds__(256) void prep_kernel(
    const float* __restrict__ P, const int* __restrict__ aff,
    const int* __restrict__ inst, ushort* __restrict__ Pb,
    int* __restrict__ keys) {
  int g = blockIdx.x * 256 + threadIdx.x;   // 524288 threads, 4 floats each
  float4 f = ((const float4*)P)[g];
  ushort4 h;
  __hip_bfloat16 b;
  b = __float2bfloat16(f.x); h.x = __builtin_bit_cast(unsigned short, b);
  b = __float2bfloat16(f.y); h.y = __builtin_bit_cast(unsigned short, b);
  b = __float2bfloat16(f.z); h.z = __builtin_bit_cast(unsigned short, b);
  b = __float2bfloat16(f.w); h.w = __builtin_bit_cast(unsigned short, b);
  ((ushort4*)Pb)[g] = h;
  if (g < BN) keys[g] = (aff[g] << 12) | inst[g];
}

// ---------------- fused GEMM + online LSE + positive sums ----------------
__global__ __launch_bounds__(512, 2) void fused_kernel(
    const ushort* __restrict__ Pb, const int* __restrict__ keys,
    float4* __restrict__ stats) {
  __shared__ __align__(16) ushort Abuf[4 * 128 * 64];   // 64KB, full K resident
  __shared__ __align__(16) ushort Bbuf[2][128 * 64];    // 2 x 16KB dbuf
  __shared__ __align__(16) int jkeysL[2][128];

  const int tid = threadIdx.x;
  const int w = tid >> 6;       // wave 0..7
  const int l = tid & 63;
  const int q = l >> 4;         // 0..3
  const int li = l & 15;
  const int iw = w >> 1;        // 0..3 : i-wave
  const int jw = w & 1;         // 0..1 : j-wave

  // XCD-friendly decomposition: chunk on pairs of XCDs
  const int bid = blockIdx.x;
  const int chunk = (bid & 7) >> 1;               // 0..3
  const int itile = ((bid >> 3) << 1) + (bid & 1); // 0..63
  const int ibase = itile * 128;
  const int jcbase = chunk * 2048;

  const int gi0 = ibase + iw * 32 + li;
  const int gi1 = gi0 + 16;
  const int keyi0 = keys[gi0];
  const int keyi1 = keys[gi1];

  const ushort* gA = Pb + (size_t)ibase * DK;

  // staging constants: thread t writes LDS 16B-block (t&7) of row (t>>3)(+64*qq)
  // content pre-swizzled: source block = (t&7) ^ (row&7)
  const int srow = tid >> 3;                           // 0..63
  const size_t srcrow = (size_t)srow * (DK * 2);
  const int sboff = ((tid & 7) ^ (srow & 7)) * 16;
  const int wavebase = w << 10;

  // ---- prologue: stage full A (4 ksteps x 2 issues) ----
#pragma unroll
  for (int ks = 0; ks < 4; ++ks) {
#pragma unroll
    for (int qq = 0; qq < 2; ++qq) {
      gload16((const char*)gA + srcrow + (size_t)qq * 64 * (DK * 2) + ks * 128 + sboff,
              (char*)Abuf + ks * 16384 + qq * 8192 + wavebase);
    }
  }
  // stage B(jt=0, ks=0)
  {
    const char* gB = (const char*)(Pb + (size_t)jcbase * DK);
    gload16(gB + srcrow + sboff, (char*)&Bbuf[0][0] + wavebase);
    gload16(gB + srcrow + (size_t)64 * (DK * 2) + sboff,
            (char*)&Bbuf[0][0] + 8192 + wavebase);
  }
  if (tid < 128) jkeysL[0][tid] = keys[jcbase + tid];
  __syncthreads();

  // operand read offsets (swizzled): row&7 == l&7 for all our rows
  const int rowA0b = (iw * 32 + li) * 128;
  const int rowA1b = rowA0b + 2048;
  const int rowBb = (jw * 64 + li) * 128;
  const int swz0 = ((0 * 4 + q) ^ (l & 7)) * 16;
  const int swz1 = ((1 * 4 + q) ^ (l & 7)) * 16;

  float m0 = NEGINF, m1 = NEGINF, s0 = 0.f, s1 = 0.f;
  float ps0 = 0.f, ps1 = 0.f, pc0 = 0.f, pc1 = 0.f;

  for (int jt = 0; jt < JTILES; ++jt) {
    const int jtb = jcbase + jt * 128;
    vfloat4 acc[2][4];
#pragma unroll
    for (int a = 0; a < 2; ++a)
#pragma unroll
      for (int b = 0; b < 4; ++b) acc[a][b] = (vfloat4){0.f, 0.f, 0.f, 0.f};

#pragma unroll
    for (int ks = 0; ks < 4; ++ks) {
      if (ks < 3) {  // prefetch next k-step of B
        const char* gB = (const char*)(Pb + (size_t)jtb * DK);
        char* dst = (char*)&Bbuf[(ks + 1) & 1][0] + wavebase;
        gload16(gB + srcrow + (ks + 1) * 128 + sboff, dst);
        gload16(gB + srcrow + (size_t)64 * (DK * 2) + (ks + 1) * 128 + sboff, dst + 8192);
      }
      const char* As = (const char*)Abuf + ks * 16384;
      const char* Bs = (const char*)&Bbuf[ks & 1][0];
#pragma unroll
      for (int kk = 0; kk < 2; ++kk) {
        const int colo = kk ? swz1 : swz0;
        vshort8 i0 = *(const vshort8*)(As + rowA0b + colo);
        vshort8 i1 = *(const vshort8*)(As + rowA1b + colo);
#pragma unroll
        for (int fj = 0; fj < 4; ++fj) {
          vshort8 jv = *(const vshort8*)(Bs + rowBb + fj * 2048 + colo);
          acc[0][fj] = __builtin_amdgcn_mfma_f32_16x16x32_bf16(jv, i0, acc[0][fj], 0, 0, 0);
          acc[1][fj] = __builtin_amdgcn_mfma_f32_16x16x32_bf16(jv, i1, acc[1][fj], 0, 0, 0);
        }
      }
      __syncthreads();
    }

    // prefetch next tile's first B chunk + keys, hidden under epilogue
    if (jt + 1 < JTILES) {
      if (tid < 128) jkeysL[(jt + 1) & 1][tid] = keys[jtb + 128 + tid];
      const char* gB = (const char*)(Pb + (size_t)(jtb + 128) * DK);
      char* dst = (char*)&Bbuf[0][0] + wavebase;
      gload16(gB + srcrow + sboff, dst);
      gload16(gB + srcrow + (size_t)64 * (DK * 2) + sboff, dst + 8192);
    }

    // ---- epilogue: self-mask, tile max, online lse, positive sums ----
    const int iwb0 = ibase + iw * 32;
    float tmax0 = NEGINF, tmax1 = NEGINF;
#pragma unroll
    for (int fj = 0; fj < 4; ++fj) {
      const int jfb = jtb + jw * 64 + fj * 16;
      if (jfb == iwb0) {
#pragma unroll
        for (int r = 0; r < 4; ++r) {
          float v = acc[0][fj][r];
          v = (q * 4 + r == li) ? NEGINF : v;
          acc[0][fj][r] = v;
          tmax0 = fmaxf(tmax0, v);
        }
      } else {
#pragma unroll
        for (int r = 0; r < 4; ++r) tmax0 = fmaxf(tmax0, acc[0][fj][r]);
      }
      if (jfb == iwb0 + 16) {
#pragma unroll
        for (int r = 0; r < 4; ++r) {
          float v = acc[1][fj][r];
          v = (q * 4 + r == li) ? NEGINF : v;
          acc[1][fj][r] = v;
          tmax1 = fmaxf(tmax1, v);
        }
      } else {
#pragma unroll
        for (int r = 0; r < 4; ++r) tmax1 = fmaxf(tmax1, acc[1][fj][r]);
      }
    }
    tmax0 = fmaxf(tmax0, __shfl_xor(tmax0, 16));
    tmax0 = fmaxf(tmax0, __shfl_xor(tmax0, 32));
    tmax1 = fmaxf(tmax1, __shfl_xor(tmax1, 16));
    tmax1 = fmaxf(tmax1, __shfl_xor(tmax1, 32));
    const float mn0 = fmaxf(m0, tmax0);
    const float mn1 = fmaxf(m1, tmax1);
    s0 *= exp2f((m0 - mn0) * KLOG2E_T);
    s1 *= exp2f((m1 - mn1) * KLOG2E_T);
    m0 = mn0; m1 = mn1;
    const float rc0 = -mn0 * KLOG2E_T;
    const float rc1 = -mn1 * KLOG2E_T;
#pragma unroll
    for (int fj = 0; fj < 4; ++fj) {
      const int4 kj = *(const int4*)&jkeysL[jt & 1][jw * 64 + fj * 16 + q * 4];
      const int kja[4] = {kj.x, kj.y, kj.z, kj.w};
#pragma unroll
      for (int r = 0; r < 4; ++r) {
        const float v0 = acc[0][fj][r];
        const float v1 = acc[1][fj][r];
        s0 += exp2f(fmaf(v0, KLOG2E_T, rc0));
        s1 += exp2f(fmaf(v1, KLOG2E_T, rc1));
        const unsigned x0 = (unsigned)(kja[r] ^ keyi0);
        const unsigned x1 = (unsigned)(kja[r] ^ keyi1);
        const bool p0 = (x0 - 1u) < 4095u;   // aff equal && inst differ
        const bool p1 = (x1 - 1u) < 4095u;
        ps0 += p0 ? v0 : 0.f;
        ps1 += p1 ? v1 : 0.f;
        pc0 += p0 ? 1.f : 0.f;
        pc1 += p1 ? 1.f : 0.f;
      }
    }
    __syncthreads();
  }

  // combine the 4 col-partitions (lanes l, l^16, l^32, l^48)
  s0 += __shfl_xor(s0, 16);  s0 += __shfl_xor(s0, 32);
  s1 += __shfl_xor(s1, 16);  s1 += __shfl_xor(s1, 32);
  ps0 += __shfl_xor(ps0, 16); ps0 += __shfl_xor(ps0, 32);
  ps1 += __shfl_xor(ps1, 16); ps1 += __shfl_xor(ps1, 32);
  pc0 += __shfl_xor(pc0, 16); pc0 += __shfl_xor(pc0, 32);
  pc1 += __shfl_xor(pc1, 16); pc1 += __shfl_xor(pc1, 32);
  if (l < 16) {
    const int slot = chunk * 2 + jw;
    stats[(size_t)slot * BN + gi0] = make_float4(m0, s0, ps0, pc0);
    stats[(size_t)slot * BN + gi1] = make_float4(m1, s1, ps1, pc1);
  }
}

// ---------------- merge partials per row + block reduce ----------------
__global__ __launch_bounds__(256) void reduce_rows(
    const float4* __restrict__ stats, float2* __restrict__ part) {
  const int i = blockIdx.x * 256 + threadIdx.x;
  float m = NEGINF, s = 0.f, ps = 0.f, pc = 0.f;
#pragma unroll
  for (int c = 0; c < 8; ++c) {
    float4 v = stats[(size_t)c * BN + i];
    float mn = fmaxf(m, v.x);
    s = s * exp2f((m - mn) * KLOG2E_T) + v.y * exp2f((v.x - mn) * KLOG2E_T);
    m = mn;
    ps += v.z;
    pc += v.w;
  }
  const float lse = m * INV_T + logf(s);
  float contrib = pc * lse - ps * INV_T;
#pragma unroll
  for (int off = 32; off > 0; off >>= 1) {
    contrib += __shfl_xor(contrib, off);
    pc += __shfl_xor(pc, off);
  }
  __shared__ float cs[4], pcs[4];
  if ((threadIdx.x & 63) == 0) {
    cs[threadIdx.x >> 6] = contrib;
    pcs[threadIdx.x >> 6] = pc;
  }
  __syncthreads();
  if (threadIdx.x == 0) {
    part[blockIdx.x] = make_float2(cs[0] + cs[1] + cs[2] + cs[3],
                                   pcs[0] + pcs[1] + pcs[2] + pcs[3]);
  }
}

__global__ void finalize(const float2* __restrict__ part, float* __restrict__ out) {
  float c = 0.f, p = 0.f;
  if (threadIdx.x < 32) {
    float2 v = part[threadIdx.x];
    c = v.x;
    p = v.y;
  }
#pragma unroll
  for (int off = 32; off > 0; off >>= 1) {
    c += __shfl_xor(c, off);
    p += __shfl_xor(p, off);
  }
  if (threadIdx.x == 0) out[0] = (p > 0.f) ? (c / p) : 0.f;
}

extern "C" void kernel_launch(void* const* d_in, const int* in_sizes, int n_in,
                              void* d_out, int out_size, void* d_ws, size_t ws_size,
                              hipStream_t stream) {
  const float* P = (const float*)d_in[0];
  const int* aff = (const int*)d_in[1];
  const int* inst = (const int*)d_in[2];
  char* ws = (char*)d_ws;
  ushort* Pb = (ushort*)ws;                                   // 4 MB
  int* keys = (int*)(ws + 4 * 1024 * 1024);                   // 32 KB
  float4* stats = (float4*)(ws + 4 * 1024 * 1024 + 32768);    // 1 MB (8 x 8192 x 16B)
  float2* part = (float2*)(ws + 4 * 1024 * 1024 + 32768 + 8 * BN * 16);
  float* out = (float*)d_out;

  prep_kernel<<<2048, 256, 0, stream>>>(P, aff, inst, Pb, keys);
  fused_kernel<<<256, 512, 0, stream>>>(Pb, keys, stats);
  reduce_rows<<<32, 256, 0, stream>>>(stats, part);
  finalize<<<1, 64, 0, stream>>>(part, out);
}